// Round 1
// baseline (286.096 us; speedup 1.0000x reference)
//
#include <hip/hip_runtime.h>

#define N_NODES 250000
#define N_EDGES 4000000
#define N_GRAPHS 512
#define NEG 0.01f
#define BINB 9
#define WIN 512
#define NBINS 489            // ceil(250000 / 512)
#define NSUB (NBINS * 4)     // dst-bin x src-quarter
#define CAPQ 2560            // per-sub-bin capacity: mean ~2045 + 11 sigma
#define PART_EPB 8192
#define PART_BLOCKS 489      // 489 * 8192 >= N_EDGES

__device__ __forceinline__ float lrelu(float v) { return v > 0.0f ? v : NEG * v; }
__device__ __forceinline__ unsigned f2b(float f) {
    unsigned u = __float_as_uint(f);
    unsigned r = ((u >> 16) & 1u) + 0x7FFFu;
    return (u + r) >> 16;
}
__device__ __forceinline__ unsigned pk(float a, float b) { return f2b(a) | (f2b(b) << 16); }
__device__ __forceinline__ float blo(unsigned p) { return __uint_as_float(p << 16); }
__device__ __forceinline__ float bhi(unsigned p) { return __uint_as_float(p & 0xFFFF0000u); }

// ---- Pack x into x16b (16 bf16 = 32 B rows); block 0 zeroes qcnt -------
__global__ __launch_bounds__(256) void pack_x(const float* __restrict__ x,
                                              unsigned* __restrict__ x16b,
                                              int* __restrict__ qcnt) {
    if (blockIdx.x == 0) {
        for (int i = threadIdx.x; i < NSUB; i += 256) qcnt[i] = 0;
    }
    int tid = blockIdx.x * blockDim.x + threadIdx.x;
    if (tid >= N_NODES * 8) return;
    int n = tid >> 3, d2 = tid & 7;
    int a = d2 * 2, b = a + 1;
    float va = (a < 13) ? x[n * 13 + a] : 0.0f;
    float vb = (b < 13) ? x[n * 13 + b] : 0.0f;
    x16b[tid] = pk(va, vb);
}

// ---- Edge binning with in-LDS sort by sub-bin (dense run writes) -------
__global__ __launch_bounds__(1024) void partition_k(const int* __restrict__ src,
                                                    const int* __restrict__ dst,
                                                    int* __restrict__ qcnt,
                                                    unsigned* __restrict__ binned) {
    __shared__ int hist[NSUB];            // later reused as scatter cursor
    __shared__ int loff[NSUB];
    __shared__ int base[NSUB];
    __shared__ unsigned ebuf[PART_EPB];
    __shared__ unsigned short subid[PART_EPB];
    __shared__ int wsum[16];
    int t = threadIdx.x;
    for (int i = t; i < NSUB; i += 1024) hist[i] = 0;
    __syncthreads();
    unsigned e0 = blockIdx.x * PART_EPB;
    int m = min((int)PART_EPB, (int)(N_EDGES - e0));
    for (int i = t; i < m; i += 1024) {
        unsigned e = e0 + i;
        int s = ((dst[e] >> BINB) << 2) | (src[e] >> 16);
        atomicAdd(&hist[s], 1);
    }
    __syncthreads();
    // exclusive scan over 1956 counters via 978 pairs + wave shuffles
    int p = 0, s0 = 0, incl = 0;
    if (t < NSUB / 2) { s0 = hist[2 * t]; p = s0 + hist[2 * t + 1]; }
    incl = p;
#pragma unroll
    for (int d = 1; d < 64; d <<= 1) {
        int u = __shfl_up(incl, d, 64);
        if ((t & 63) >= d) incl += u;
    }
    if ((t & 63) == 63) wsum[t >> 6] = incl;
    __syncthreads();
    if (t == 0) {
        int r = 0;
#pragma unroll
        for (int i = 0; i < 16; i++) { int s = wsum[i]; wsum[i] = r; r += s; }
    }
    __syncthreads();
    if (t < NSUB / 2) {
        int ex = incl + wsum[t >> 6] - p;
        loff[2 * t] = ex;
        loff[2 * t + 1] = ex + s0;
    }
    __syncthreads();
    // reserve global chunks (uses hist), then hist becomes cursor = loff
    for (int i = t; i < NSUB; i += 1024) {
        int h = hist[i];
        base[i] = (h > 0) ? atomicAdd(&qcnt[i], h) : 0;
    }
    __syncthreads();
    for (int i = t; i < NSUB; i += 1024) hist[i] = loff[i];
    __syncthreads();
    // pass 2: re-read edges, scatter into LDS sorted-by-sub order
    for (int i = t; i < m; i += 1024) {
        unsigned e = e0 + i;
        int d = dst[e], sv = src[e];
        int s = ((d >> BINB) << 2) | (sv >> 16);
        int pos = atomicAdd(&hist[s], 1);
        ebuf[pos] = ((unsigned)(d & (WIN - 1)) << 18) | (unsigned)sv;
        subid[pos] = (unsigned short)s;
    }
    __syncthreads();
    // write-out: consecutive lanes hit consecutive addresses of each run
    for (int j = t; j < m; j += 1024) {
        int s = subid[j];
        binned[(size_t)s * CAPQ + base[s] + (j - loff[s])] = ebuf[j];
    }
}

// ---- Counting sort each sub-bin by dst + fused layer-1 aggregation -----
// Restructured: the 4 src-quarter sub-bins of a dst window are processed
// CONCURRENTLY by 4 groups of 256 threads (vs serially by all 1024).
// Barriers drop ~24 -> 6 per block; the fused gather covers all 4 sub-bins
// in one phase (~16 independent 16B loads/thread vs 4) for deeper MLP.
// No LDS staging buffer: scatter re-reads its (L1/L2-hot) binned slice,
// keeping LDS at ~56 KB -> 2 blocks/CU.
__global__ __launch_bounds__(1024) void sortagg_k(const unsigned* __restrict__ x16b,
                                                  unsigned* __restrict__ binned,
                                                  const int* __restrict__ qcnt,
                                                  int* __restrict__ offs,
                                                  float* __restrict__ cntf,
                                                  float* __restrict__ agg) {
    __shared__ unsigned srt[4][CAPQ];
    __shared__ int hist[4][WIN];
    __shared__ int cur[4][WIN];
    __shared__ int wsum[16];
    int t = threadIdx.x;
    int bin = blockIdx.x;
    int g = t >> 8;        // src-quarter group (0..3)
    int tl = t & 255;      // lane within group
    int sub = (bin << 2) | g;
    int cnt = qcnt[sub];
    unsigned* bp = binned + (size_t)sub * CAPQ;
    int lane = t & 63, wv = t >> 6;   // wv: global wave id 0..15; group = wv>>2

    // phase 1: zero histograms
    for (int i = t; i < 4 * WIN; i += 1024) (&hist[0][0])[i] = 0;
    __syncthreads();

    // phase 2: histogram pass (group-parallel over the 4 sub-bins)
    for (int i = tl; i < cnt; i += 256) {
        unsigned w = bp[i];
        atomicAdd(&hist[g][w >> 18], 1);
    }
    __syncthreads();

    // phase 3: per-group exclusive scan over 512 counters
    // thread tl handles entries 2tl, 2tl+1; 4 waves per group
    int s0 = hist[g][2 * tl];
    int p = s0 + hist[g][2 * tl + 1];
    int incl = p;
#pragma unroll
    for (int d = 1; d < 64; d <<= 1) {
        int u = __shfl_up(incl, d, 64);
        if (lane >= d) incl += u;
    }
    if (lane == 63) wsum[wv] = incl;
    __syncthreads();
    if (t == 0) {
#pragma unroll
        for (int gg = 0; gg < 4; gg++) {
            int r = 0;
#pragma unroll
            for (int i = 0; i < 4; i++) { int s = wsum[gg * 4 + i]; wsum[gg * 4 + i] = r; r += s; }
        }
    }
    __syncthreads();
    {
        int ex = incl + wsum[wv] - p;          // exclusive start of entry 2tl
        cur[g][2 * tl] = ex;
        cur[g][2 * tl + 1] = ex + s0;
        offs[(size_t)sub * 513 + 2 * tl] = ex;
        offs[(size_t)sub * 513 + 2 * tl + 1] = ex + s0;
        if (tl == 0) offs[(size_t)sub * 513 + WIN] = cnt;
    }
    __syncthreads();

    // phase 4: scatter into sorted order (re-read L1/L2-hot binned slice)
    for (int i = tl; i < cnt; i += 256) {
        unsigned w = bp[i];
        int pos = atomicAdd(&cur[g][w >> 18], 1);
        srt[g][pos] = w;
    }
    __syncthreads();

    // phase 5: writeback sorted runs (group-parallel, coalesced) +
    // fused layer-1 gather across ALL 4 sub-bins (node-parallel)
    for (int i = tl; i < cnt; i += 256) bp[i] = srt[g][i];

    int f = t & (WIN - 1), l = t >> 9;
    float a0 = 0, a1 = 0, a2 = 0, a3 = 0, a4 = 0, a5 = 0, a6 = 0, a7 = 0;
    int deg = 0;
    for (int q = 0; q < 4; q++) {
        int e_ = cur[q][f];          // end (cursor after scatter)
        int h = hist[q][f];
        int s_ = e_ - h;             // start
        deg += h;
        const unsigned* sp = srt[q];
        int k = s_;
        for (; k + 4 <= e_; k += 4) {
            unsigned w0 = sp[k], w1 = sp[k + 1], w2 = sp[k + 2], w3 = sp[k + 3];
            uint4 v0 = *(const uint4*)&x16b[(size_t)(w0 & 0x3FFFFu) * 8u + (unsigned)(l * 4)];
            uint4 v1 = *(const uint4*)&x16b[(size_t)(w1 & 0x3FFFFu) * 8u + (unsigned)(l * 4)];
            uint4 v2 = *(const uint4*)&x16b[(size_t)(w2 & 0x3FFFFu) * 8u + (unsigned)(l * 4)];
            uint4 v3 = *(const uint4*)&x16b[(size_t)(w3 & 0x3FFFFu) * 8u + (unsigned)(l * 4)];
            a0 += blo(v0.x) + blo(v1.x) + blo(v2.x) + blo(v3.x);
            a1 += bhi(v0.x) + bhi(v1.x) + bhi(v2.x) + bhi(v3.x);
            a2 += blo(v0.y) + blo(v1.y) + blo(v2.y) + blo(v3.y);
            a3 += bhi(v0.y) + bhi(v1.y) + bhi(v2.y) + bhi(v3.y);
            a4 += blo(v0.z) + blo(v1.z) + blo(v2.z) + blo(v3.z);
            a5 += bhi(v0.z) + bhi(v1.z) + bhi(v2.z) + bhi(v3.z);
            a6 += blo(v0.w) + blo(v1.w) + blo(v2.w) + blo(v3.w);
            a7 += bhi(v0.w) + bhi(v1.w) + bhi(v2.w) + bhi(v3.w);
        }
        for (; k < e_; k++) {
            unsigned w = sp[k];
            uint4 v4 = *(const uint4*)&x16b[(size_t)(w & 0x3FFFFu) * 8u + (unsigned)(l * 4)];
            a0 += blo(v4.x); a1 += bhi(v4.x); a2 += blo(v4.y); a3 += bhi(v4.y);
            a4 += blo(v4.z); a5 += bhi(v4.z); a6 += blo(v4.w); a7 += bhi(v4.w);
        }
    }
    int gn = (bin << BINB) + f;
    if (gn < N_NODES) {
        size_t b = (size_t)gn * 13;
        if (l == 0) {
            agg[b + 0] = a0; agg[b + 1] = a1; agg[b + 2] = a2; agg[b + 3] = a3;
            agg[b + 4] = a4; agg[b + 5] = a5; agg[b + 6] = a6; agg[b + 7] = a7;
            cntf[gn] = (float)deg;
        } else {
            agg[b + 8] = a0; agg[b + 9] = a1; agg[b + 10] = a2;
            agg[b + 11] = a3; agg[b + 12] = a4;
        }
    }
}

// ---- Node linear 1: h1, y2b, z2 ----------------------------------------
// __launch_bounds__(256) is load-bearing: without it hipcc compiles for
// 1024-thread worst case -> 64 VGPR cap -> ~55 live floats spill to
// scratch (~165 MB of spill traffic, 54 us). With it: no spill.
__global__ __launch_bounds__(256) void fused1(const float* __restrict__ agg,
                                              const float* __restrict__ x,
                                              const float* __restrict__ cntf,
                                              const float* __restrict__ W1l,
                                              const float* __restrict__ b1,
                                              const float* __restrict__ W1r,
                                              const float* __restrict__ W2l,
                                              const float* __restrict__ W2r,
                                              unsigned* __restrict__ y2b,
                                              float* __restrict__ z2) {
    __shared__ float sWl[208], sWr[208], sb[16], sA[128], sB[128];
    for (int i = threadIdx.x; i < 208; i += blockDim.x) { sWl[i] = W1l[i]; sWr[i] = W1r[i]; }
    for (int i = threadIdx.x; i < 128; i += blockDim.x) { sA[i] = W2l[i]; sB[i] = W2r[i]; }
    if (threadIdx.x < 16) sb[threadIdx.x] = b1[threadIdx.x];
    __syncthreads();
    int n = blockIdx.x * blockDim.x + threadIdx.x;
    if (n >= N_NODES) return;
    float inv = 1.0f / fmaxf(cntf[n], 1.0f);
    float a[13], xv[13];
#pragma unroll
    for (int i = 0; i < 13; i++) { a[i] = agg[n * 13 + i] * inv; xv[i] = x[n * 13 + i]; }
    float h[16];
#pragma unroll
    for (int o = 0; o < 16; o++) {
        float acc = sb[o];
#pragma unroll
        for (int i = 0; i < 13; i++) acc += a[i] * sWl[i * 16 + o] + xv[i] * sWr[i * 16 + o];
        h[o] = lrelu(acc);
    }
    float ya[8];
#pragma unroll
    for (int o2 = 0; o2 < 8; o2++) {
        float y = 0.0f, za = 0.0f;
#pragma unroll
        for (int o = 0; o < 16; o++) { y += h[o] * sA[o * 8 + o2]; za += h[o] * sB[o * 8 + o2]; }
        ya[o2] = y;
        z2[n * 8 + o2] = za;
    }
    uint4 out;
    out.x = pk(ya[0], ya[1]); out.y = pk(ya[2], ya[3]);
    out.z = pk(ya[4], ya[5]); out.w = pk(ya[6], ya[7]);
    *(uint4*)&y2b[(size_t)n * 4u] = out;
}

// ---- Layer-2 gather + fused epilogue: h2 (in z2), y3b ------------------
__global__ __launch_bounds__(256) void agg8f_k(const unsigned* __restrict__ y2b,
                                               const unsigned* __restrict__ binned,
                                               const int* __restrict__ offs,
                                               const float* __restrict__ cntf,
                                               const float* __restrict__ b2,
                                               const float* __restrict__ W3l,
                                               float* __restrict__ z2h2,
                                               unsigned* __restrict__ y3b,
                                               float* __restrict__ pool) {
    __shared__ float sb[8], sW3[32];
    if (blockIdx.x == 0) {
        for (int i = threadIdx.x; i < N_GRAPHS * 5; i += 256) pool[i] = 0.0f;
    }
    if (threadIdx.x < 8) sb[threadIdx.x] = b2[threadIdx.x];
    if (threadIdx.x < 32) sW3[threadIdx.x] = W3l[threadIdx.x];
    __syncthreads();
    int g = blockIdx.x * 256 + threadIdx.x;
    if (g >= N_NODES) return;
    int bin = g >> BINB, f = g & (WIN - 1);
    float a0 = 0, a1 = 0, a2 = 0, a3 = 0, a4 = 0, a5 = 0, a6 = 0, a7 = 0;
#pragma unroll
    for (int q = 0; q < 4; q++) {
        int sub = (bin << 2) | q;
        const int* o = offs + (size_t)sub * 513;
        int s = o[f], e = o[f + 1];
        const unsigned* bp = binned + (size_t)sub * CAPQ;
        int k = s;
        for (; k + 4 <= e; k += 4) {
            unsigned w0 = bp[k], w1 = bp[k + 1], w2 = bp[k + 2], w3 = bp[k + 3];
            uint4 v0 = *(const uint4*)&y2b[(size_t)(w0 & 0x3FFFFu) * 4u];
            uint4 v1 = *(const uint4*)&y2b[(size_t)(w1 & 0x3FFFFu) * 4u];
            uint4 v2 = *(const uint4*)&y2b[(size_t)(w2 & 0x3FFFFu) * 4u];
            uint4 v3 = *(const uint4*)&y2b[(size_t)(w3 & 0x3FFFFu) * 4u];
            a0 += blo(v0.x) + blo(v1.x) + blo(v2.x) + blo(v3.x);
            a1 += bhi(v0.x) + bhi(v1.x) + bhi(v2.x) + bhi(v3.x);
            a2 += blo(v0.y) + blo(v1.y) + blo(v2.y) + blo(v3.y);
            a3 += bhi(v0.y) + bhi(v1.y) + bhi(v2.y) + bhi(v3.y);
            a4 += blo(v0.z) + blo(v1.z) + blo(v2.z) + blo(v3.z);
            a5 += bhi(v0.z) + bhi(v1.z) + bhi(v2.z) + bhi(v3.z);
            a6 += blo(v0.w) + blo(v1.w) + blo(v2.w) + blo(v3.w);
            a7 += bhi(v0.w) + bhi(v1.w) + bhi(v2.w) + bhi(v3.w);
        }
        for (; k < e; k++) {
            uint4 v = *(const uint4*)&y2b[(size_t)(bp[k] & 0x3FFFFu) * 4u];
            a0 += blo(v.x); a1 += bhi(v.x); a2 += blo(v.y); a3 += bhi(v.y);
            a4 += blo(v.z); a5 += bhi(v.z); a6 += blo(v.w); a7 += bhi(v.w);
        }
    }
    float inv = 1.0f / fmaxf(cntf[g], 1.0f);
    float h2v[8];
    float s8[8] = {a0, a1, a2, a3, a4, a5, a6, a7};
#pragma unroll
    for (int j = 0; j < 8; j++) {
        float v = s8[j] * inv + sb[j] + z2h2[(size_t)g * 8 + j];
        h2v[j] = lrelu(v);
        z2h2[(size_t)g * 8 + j] = h2v[j];
    }
    float y[4];
#pragma unroll
    for (int k = 0; k < 4; k++) {
        float acc = 0.0f;
#pragma unroll
        for (int j = 0; j < 8; j++) acc += h2v[j] * sW3[j * 4 + k];
        y[k] = acc;
    }
    uint2 out;
    out.x = pk(y[0], y[1]); out.y = pk(y[2], y[3]);
    *(uint2*)&y3b[(size_t)g * 2u] = out;
}

// ---- Layer-3 gather + fused epilogue + pooling -------------------------
__global__ __launch_bounds__(256) void agg4pool_k(const unsigned* __restrict__ y3b,
                                                  const unsigned* __restrict__ binned,
                                                  const int* __restrict__ offs,
                                                  const float* __restrict__ cntf,
                                                  const float* __restrict__ h2,
                                                  const float* __restrict__ W3r,
                                                  const float* __restrict__ b3,
                                                  const int* __restrict__ batch,
                                                  float* __restrict__ pool,
                                                  float* __restrict__ gcnt) {
    __shared__ float sW[32], sb[4];
    __shared__ float lp[16][4];
    __shared__ float lc[16];
    __shared__ int sbase;
    if (threadIdx.x < 32) sW[threadIdx.x] = W3r[threadIdx.x];
    if (threadIdx.x < 4) sb[threadIdx.x] = b3[threadIdx.x];
    if (threadIdx.x < 16) {
        lc[threadIdx.x] = 0.0f;
        for (int k = 0; k < 4; k++) lp[threadIdx.x][k] = 0.0f;
    }
    int n0 = blockIdx.x * 256;
    if (threadIdx.x == 0) sbase = batch[n0 < N_NODES ? n0 : N_NODES - 1];
    __syncthreads();
    int g = n0 + threadIdx.x;
    if (g < N_NODES) {
        int bin = g >> BINB, f = g & (WIN - 1);
        float a0 = 0, a1 = 0, a2 = 0, a3 = 0;
#pragma unroll
        for (int q = 0; q < 4; q++) {
            int sub = (bin << 2) | q;
            const int* o = offs + (size_t)sub * 513;
            int s = o[f], e = o[f + 1];
            const unsigned* bp = binned + (size_t)sub * CAPQ;
            int k = s;
            for (; k + 4 <= e; k += 4) {
                unsigned w0 = bp[k], w1 = bp[k + 1], w2 = bp[k + 2], w3 = bp[k + 3];
                uint2 v0 = *(const uint2*)&y3b[(size_t)(w0 & 0x3FFFFu) * 2u];
                uint2 v1 = *(const uint2*)&y3b[(size_t)(w1 & 0x3FFFFu) * 2u];
                uint2 v2 = *(const uint2*)&y3b[(size_t)(w2 & 0x3FFFFu) * 2u];
                uint2 v3 = *(const uint2*)&y3b[(size_t)(w3 & 0x3FFFFu) * 2u];
                a0 += blo(v0.x) + blo(v1.x) + blo(v2.x) + blo(v3.x);
                a1 += bhi(v0.x) + bhi(v1.x) + bhi(v2.x) + bhi(v3.x);
                a2 += blo(v0.y) + blo(v1.y) + blo(v2.y) + blo(v3.y);
                a3 += bhi(v0.y) + bhi(v1.y) + bhi(v2.y) + bhi(v3.y);
            }
            for (; k < e; k++) {
                uint2 v = *(const uint2*)&y3b[(size_t)(bp[k] & 0x3FFFFu) * 2u];
                a0 += blo(v.x); a1 += bhi(v.x); a2 += blo(v.y); a3 += bhi(v.y);
            }
        }
        float inv = 1.0f / fmaxf(cntf[g], 1.0f);
        float s4[4] = {a0, a1, a2, a3};
        float h2v[8];
#pragma unroll
        for (int j = 0; j < 8; j++) h2v[j] = h2[(size_t)g * 8 + j];
        int b = batch[g];
        int off = b - sbase;
        bool local = (off >= 0 && off < 16);
#pragma unroll
        for (int k = 0; k < 4; k++) {
            float z = 0.0f;
#pragma unroll
            for (int j = 0; j < 8; j++) z += h2v[j] * sW[j * 4 + k];
            float v = s4[k] * inv + sb[k] + z;
            if (local) atomicAdd(&lp[off][k], v);
            else atomicAdd(&pool[b * 4 + k], v);
        }
        if (local) atomicAdd(&lc[off], 1.0f);
        else atomicAdd(&gcnt[b], 1.0f);
    }
    __syncthreads();
    if (threadIdx.x < 16) {
        int b = sbase + threadIdx.x;
        float c = lc[threadIdx.x];
        if (c > 0.0f && b < N_GRAPHS) {
            atomicAdd(&gcnt[b], c);
            for (int k = 0; k < 4; k++) atomicAdd(&pool[b * 4 + k], lp[threadIdx.x][k]);
        }
    }
}

__global__ __launch_bounds__(256) void final_k(const float* __restrict__ pool,
                                               const float* __restrict__ gcnt,
                                               const float* __restrict__ Wc,
                                               const float* __restrict__ bc,
                                               float* __restrict__ out) {
    int g = blockIdx.x * blockDim.x + threadIdx.x;
    if (g >= N_GRAPHS) return;
    float inv = 1.0f / fmaxf(gcnt[g], 1.0f);
    float acc = bc[0];
#pragma unroll
    for (int k = 0; k < 4; k++) {
        float ap = pool[g * 4 + k];
        acc += ap * inv * Wc[k] + ap * Wc[4 + k];
    }
    out[g] = acc;
}

extern "C" void kernel_launch(void* const* d_in, const int* in_sizes, int n_in,
                              void* d_out, int out_size, void* d_ws, size_t ws_size,
                              hipStream_t stream) {
    const float* x = (const float*)d_in[0];
    const int* ei = (const int*)d_in[1];
    const int* src = ei;
    const int* dst = ei + N_EDGES;
    const int* batch = (const int*)d_in[2];
    const float* W1l = (const float*)d_in[3];
    const float* b1 = (const float*)d_in[4];
    const float* W1r = (const float*)d_in[5];
    const float* W2l = (const float*)d_in[6];
    const float* b2 = (const float*)d_in[7];
    const float* W2r = (const float*)d_in[8];
    const float* W3l = (const float*)d_in[9];
    const float* b3 = (const float*)d_in[10];
    const float* W3r = (const float*)d_in[11];
    const float* Wc = (const float*)d_in[12];
    const float* bc = (const float*)d_in[13];
    float* out = (float*)d_out;

    const size_t N = N_NODES;
    unsigned* binned = (unsigned*)d_ws;                 // NSUB*CAPQ u32 ~= 20 MB
    int* qcnt = (int*)(binned + (size_t)NSUB * CAPQ);   // 2048 ints
    int* offs = qcnt + 2048;                            // NSUB*513 ints ~= 4 MB
    float* fbase = (float*)(offs + (size_t)NSUB * 513);
    float* agg = fbase;                         // 13N floats
    float* cntf = fbase + 13 * N;               // N
    float* z2 = cntf + N;                       // 8N (becomes h2 in place)
    unsigned* x16b = (unsigned*)(z2 + 8 * N);   // 8N u32
    unsigned* y2b = x16b + 8 * N;               // 4N u32
    unsigned* y3b = y2b + 4 * N;                // 2N u32
    float* pool = (float*)(y3b + 2 * N);        // 2048 (gcnt follows)
    float* gcnt = pool + N_GRAPHS * 4;          // 512

    const int TPB = 256;
    const int NB = (N_NODES + TPB - 1) / TPB;

    // 7 dispatches; zeroing folded into producers.
    pack_x<<<(N_NODES * 8 + TPB - 1) / TPB, TPB, 0, stream>>>(x, x16b, qcnt);
    partition_k<<<PART_BLOCKS, 1024, 0, stream>>>(src, dst, qcnt, binned);
    sortagg_k<<<NBINS, 1024, 0, stream>>>(x16b, binned, qcnt, offs, cntf, agg);
    fused1<<<NB, TPB, 0, stream>>>(agg, x, cntf, W1l, b1, W1r, W2l, W2r, y2b, z2);
    agg8f_k<<<NB, TPB, 0, stream>>>(y2b, binned, offs, cntf, b2, W3l, z2, y3b, pool);
    agg4pool_k<<<NB, TPB, 0, stream>>>(y3b, binned, offs, cntf, z2, W3r, b3, batch, pool, gcnt);
    final_k<<<2, TPB, 0, stream>>>(pool, gcnt, Wc, bc, out);
}

// Round 2
// 282.118 us; speedup vs baseline: 1.0141x; 1.0141x over previous
//
#include <hip/hip_runtime.h>

#define N_NODES 250000
#define N_EDGES 4000000
#define N_GRAPHS 512
#define NEG 0.01f
#define BINB 9
#define WIN 512
#define NBINS 489            // ceil(250000 / 512)
#define NSUB (NBINS * 4)     // dst-bin x src-quarter
#define CAPQ 2560            // per-sub-bin capacity: mean ~2045 + 11 sigma
#define PART_EPB 8192
#define PART_BLOCKS 489      // 489 * 8192 >= N_EDGES

__device__ __forceinline__ float lrelu(float v) { return v > 0.0f ? v : NEG * v; }
__device__ __forceinline__ unsigned f2b(float f) {
    unsigned u = __float_as_uint(f);
    unsigned r = ((u >> 16) & 1u) + 0x7FFFu;
    return (u + r) >> 16;
}
__device__ __forceinline__ unsigned pk(float a, float b) { return f2b(a) | (f2b(b) << 16); }
__device__ __forceinline__ float blo(unsigned p) { return __uint_as_float(p << 16); }
__device__ __forceinline__ float bhi(unsigned p) { return __uint_as_float(p & 0xFFFF0000u); }

// ---- Pack x into x16b (16 bf16 = 32 B rows); block 0 zeroes qcnt -------
__global__ __launch_bounds__(256) void pack_x(const float* __restrict__ x,
                                              unsigned* __restrict__ x16b,
                                              int* __restrict__ qcnt) {
    if (blockIdx.x == 0) {
        for (int i = threadIdx.x; i < NSUB; i += 256) qcnt[i] = 0;
    }
    int tid = blockIdx.x * blockDim.x + threadIdx.x;
    if (tid >= N_NODES * 8) return;
    int n = tid >> 3, d2 = tid & 7;
    int a = d2 * 2, b = a + 1;
    float va = (a < 13) ? x[n * 13 + a] : 0.0f;
    float vb = (b < 13) ? x[n * 13 + b] : 0.0f;
    x16b[tid] = pk(va, vb);
}

// ---- Edge binning with in-LDS sort by sub-bin (dense run writes) -------
__global__ __launch_bounds__(1024) void partition_k(const int* __restrict__ src,
                                                    const int* __restrict__ dst,
                                                    int* __restrict__ qcnt,
                                                    unsigned* __restrict__ binned) {
    __shared__ int hist[NSUB];            // later reused as scatter cursor
    __shared__ int loff[NSUB];
    __shared__ int base[NSUB];
    __shared__ unsigned ebuf[PART_EPB];
    __shared__ unsigned short subid[PART_EPB];
    __shared__ int wsum[16];
    int t = threadIdx.x;
    for (int i = t; i < NSUB; i += 1024) hist[i] = 0;
    __syncthreads();
    unsigned e0 = blockIdx.x * PART_EPB;
    int m = min((int)PART_EPB, (int)(N_EDGES - e0));
    for (int i = t; i < m; i += 1024) {
        unsigned e = e0 + i;
        int s = ((dst[e] >> BINB) << 2) | (src[e] >> 16);
        atomicAdd(&hist[s], 1);
    }
    __syncthreads();
    // exclusive scan over 1956 counters via 978 pairs + wave shuffles
    int p = 0, s0 = 0, incl = 0;
    if (t < NSUB / 2) { s0 = hist[2 * t]; p = s0 + hist[2 * t + 1]; }
    incl = p;
#pragma unroll
    for (int d = 1; d < 64; d <<= 1) {
        int u = __shfl_up(incl, d, 64);
        if ((t & 63) >= d) incl += u;
    }
    if ((t & 63) == 63) wsum[t >> 6] = incl;
    __syncthreads();
    if (t == 0) {
        int r = 0;
#pragma unroll
        for (int i = 0; i < 16; i++) { int s = wsum[i]; wsum[i] = r; r += s; }
    }
    __syncthreads();
    if (t < NSUB / 2) {
        int ex = incl + wsum[t >> 6] - p;
        loff[2 * t] = ex;
        loff[2 * t + 1] = ex + s0;
    }
    __syncthreads();
    // reserve global chunks (uses hist), then hist becomes cursor = loff
    for (int i = t; i < NSUB; i += 1024) {
        int h = hist[i];
        base[i] = (h > 0) ? atomicAdd(&qcnt[i], h) : 0;
    }
    __syncthreads();
    for (int i = t; i < NSUB; i += 1024) hist[i] = loff[i];
    __syncthreads();
    // pass 2: re-read edges, scatter into LDS sorted-by-sub order
    for (int i = t; i < m; i += 1024) {
        unsigned e = e0 + i;
        int d = dst[e], sv = src[e];
        int s = ((d >> BINB) << 2) | (sv >> 16);
        int pos = atomicAdd(&hist[s], 1);
        ebuf[pos] = ((unsigned)(d & (WIN - 1)) << 18) | (unsigned)sv;
        subid[pos] = (unsigned short)s;
    }
    __syncthreads();
    // write-out: consecutive lanes hit consecutive addresses of each run
    for (int j = t; j < m; j += 1024) {
        int s = subid[j];
        binned[(size_t)s * CAPQ + base[s] + (j - loff[s])] = ebuf[j];
    }
}

// ---- Counting sort each sub-bin by dst + fused layer-1 aggregation -----
// Round-0 structure (serial q, phase-confined gather -> preserves the L2
// locality that the round-1 restructure destroyed: FETCH 49 -> 149 MB).
// New: T14 async-STAGE split. The global loads for sub-bin q+1 are ISSUED
// into registers before the scatter of q; the LDS write + histogram
// atomics (double-buffered hist) land after the gather of q. The ~500cy
// global latency hides under scan+scatter+gather instead of sitting
// exposed between two barriers. Static reg names sw0..sw2 (no dynamic
// indexing -> no scratch).
__global__ __launch_bounds__(1024) void sortagg_k(const unsigned* __restrict__ x16b,
                                                  unsigned* __restrict__ binned,
                                                  const int* __restrict__ qcnt,
                                                  int* __restrict__ offs,
                                                  float* __restrict__ cntf,
                                                  float* __restrict__ agg) {
    __shared__ unsigned stg[CAPQ];
    __shared__ unsigned srt[CAPQ];
    __shared__ int histb[2][WIN];        // double-buffered per-q histogram
    __shared__ int cur[WIN];
    __shared__ int wsum[8];
    int t = threadIdx.x;
    int bin = blockIdx.x;
    int f = t & (WIN - 1), l = t >> 9;
    int lane = t & 63, wv = t >> 6;
    int cq[4];
#pragma unroll
    for (int q = 0; q < 4; q++) cq[q] = qcnt[(bin << 2) | q];

    float a0 = 0, a1 = 0, a2 = 0, a3 = 0, a4 = 0, a5 = 0, a6 = 0, a7 = 0;
    int deg = 0;

    // prologue: zero hist[0], stage sub-bin 0 (exposed once, not per-q)
    if (t < WIN) histb[0][t] = 0;
    __syncthreads();
    {
        const unsigned* bp0 = binned + (size_t)(bin << 2) * CAPQ;
        for (int i = t; i < cq[0]; i += 1024) {
            unsigned w = bp0[i];
            stg[i] = w;
            atomicAdd(&histb[0][w >> 18], 1);
        }
    }
    __syncthreads();

    for (int q = 0; q < 4; q++) {
        int cnt = cq[q];
        int sub = (bin << 2) | q;
        int* hb = histb[q & 1];
        int* hn = histb[(q & 1) ^ 1];
        unsigned* bp = binned + (size_t)sub * CAPQ;

        // scan: waves 0..7 scan hb (512 counters); waves 8..15 zero hn
        int v = 0;
        if (t < WIN) v = hb[t];
        else hn[t - WIN] = 0;
#pragma unroll
        for (int d = 1; d < 64; d <<= 1) {
            int u = __shfl_up(v, d, 64);
            if (lane >= d) v += u;
        }
        if (t < WIN && lane == 63) wsum[wv] = v;
        __syncthreads();
        if (t == 0) {
            int r = 0;
#pragma unroll
            for (int i = 0; i < 8; i++) { int s = wsum[i]; wsum[i] = r; r += s; }
        }
        __syncthreads();
        if (t < WIN) {
            int incl = v + wsum[wv];
            int ex = incl - hb[t];
            cur[t] = ex;
            offs[(size_t)sub * 513 + t] = ex;
            deg += hb[t];
        }
        if (t == 0) offs[(size_t)sub * 513 + WIN] = cnt;
        __syncthreads();

        // stage-ISSUE for q+1: fire the global loads now; values used only
        // after the gather. Latency hides under scatter + gather.
        unsigned sw0 = 0, sw1 = 0, sw2 = 0;
        int c1 = (q < 3) ? cq[q + 1] : 0;
        const unsigned* bpn = binned + (size_t)(sub + 1) * CAPQ;
        if (t < c1) sw0 = bpn[t];
        if (t + 1024 < c1) sw1 = bpn[t + 1024];
        if (t + 2048 < c1) sw2 = bpn[t + 2048];

        // scatter stg -> srt (sorted by dst-within-window)
        for (int i = t; i < cnt; i += 1024) {
            unsigned w = stg[i];
            int pos = atomicAdd(&cur[w >> 18], 1);
            srt[pos] = w;
        }
        __syncthreads();

        // writeback sorted run (consumed by layer-2/3 gather kernels)
        for (int i = t; i < cnt; i += 1024) bp[i] = srt[i];

        // fused layer-1 gather from LDS-resident sorted run (phase-confined:
        // whole block reads one 2MB x16b quarter -> stays L2-resident)
        int e_ = cur[f];
        int s_ = e_ - hb[f];
        int k = s_;
        for (; k + 4 <= e_; k += 4) {
            unsigned w0 = srt[k], w1 = srt[k + 1], w2 = srt[k + 2], w3 = srt[k + 3];
            uint4 v0 = *(const uint4*)&x16b[(size_t)(w0 & 0x3FFFFu) * 8u + (unsigned)(l * 4)];
            uint4 v1 = *(const uint4*)&x16b[(size_t)(w1 & 0x3FFFFu) * 8u + (unsigned)(l * 4)];
            uint4 v2 = *(const uint4*)&x16b[(size_t)(w2 & 0x3FFFFu) * 8u + (unsigned)(l * 4)];
            uint4 v3 = *(const uint4*)&x16b[(size_t)(w3 & 0x3FFFFu) * 8u + (unsigned)(l * 4)];
            a0 += blo(v0.x) + blo(v1.x) + blo(v2.x) + blo(v3.x);
            a1 += bhi(v0.x) + bhi(v1.x) + bhi(v2.x) + bhi(v3.x);
            a2 += blo(v0.y) + blo(v1.y) + blo(v2.y) + blo(v3.y);
            a3 += bhi(v0.y) + bhi(v1.y) + bhi(v2.y) + bhi(v3.y);
            a4 += blo(v0.z) + blo(v1.z) + blo(v2.z) + blo(v3.z);
            a5 += bhi(v0.z) + bhi(v1.z) + bhi(v2.z) + bhi(v3.z);
            a6 += blo(v0.w) + blo(v1.w) + blo(v2.w) + blo(v3.w);
            a7 += bhi(v0.w) + bhi(v1.w) + bhi(v2.w) + bhi(v3.w);
        }
        for (; k < e_; k++) {
            unsigned w = srt[k];
            uint4 v4 = *(const uint4*)&x16b[(size_t)(w & 0x3FFFFu) * 8u + (unsigned)(l * 4)];
            a0 += blo(v4.x); a1 += bhi(v4.x); a2 += blo(v4.y); a3 += bhi(v4.y);
            a4 += blo(v4.z); a5 += bhi(v4.z); a6 += blo(v4.w); a7 += bhi(v4.w);
        }

        // stage-WRITE for q+1: commit prefetched words to LDS + histogram.
        // stg was fully consumed by the scatter above; hn was zeroed in the
        // scan phase. Barrier below publishes both for the next iteration.
        if (t < c1) { stg[t] = sw0; atomicAdd(&hn[sw0 >> 18], 1); }
        if (t + 1024 < c1) { stg[t + 1024] = sw1; atomicAdd(&hn[sw1 >> 18], 1); }
        if (t + 2048 < c1) { stg[t + 2048] = sw2; atomicAdd(&hn[sw2 >> 18], 1); }
        __syncthreads();
    }

    int gn = (bin << BINB) + f;
    if (gn < N_NODES) {
        size_t b = (size_t)gn * 13;
        if (l == 0) {
            agg[b + 0] = a0; agg[b + 1] = a1; agg[b + 2] = a2; agg[b + 3] = a3;
            agg[b + 4] = a4; agg[b + 5] = a5; agg[b + 6] = a6; agg[b + 7] = a7;
            cntf[gn] = (float)deg;
        } else {
            agg[b + 8] = a0; agg[b + 9] = a1; agg[b + 10] = a2;
            agg[b + 11] = a3; agg[b + 12] = a4;
        }
    }
}

// ---- Node linear 1: h1, y2b, z2 ----------------------------------------
// __launch_bounds__(256) is load-bearing: without it hipcc compiles for
// 1024-thread worst case -> 64 VGPR cap -> ~55 live floats spill to
// scratch (~165 MB of spill traffic, 54 us). With it: no spill.
__global__ __launch_bounds__(256) void fused1(const float* __restrict__ agg,
                                              const float* __restrict__ x,
                                              const float* __restrict__ cntf,
                                              const float* __restrict__ W1l,
                                              const float* __restrict__ b1,
                                              const float* __restrict__ W1r,
                                              const float* __restrict__ W2l,
                                              const float* __restrict__ W2r,
                                              unsigned* __restrict__ y2b,
                                              float* __restrict__ z2) {
    __shared__ float sWl[208], sWr[208], sb[16], sA[128], sB[128];
    for (int i = threadIdx.x; i < 208; i += blockDim.x) { sWl[i] = W1l[i]; sWr[i] = W1r[i]; }
    for (int i = threadIdx.x; i < 128; i += blockDim.x) { sA[i] = W2l[i]; sB[i] = W2r[i]; }
    if (threadIdx.x < 16) sb[threadIdx.x] = b1[threadIdx.x];
    __syncthreads();
    int n = blockIdx.x * blockDim.x + threadIdx.x;
    if (n >= N_NODES) return;
    float inv = 1.0f / fmaxf(cntf[n], 1.0f);
    float a[13], xv[13];
#pragma unroll
    for (int i = 0; i < 13; i++) { a[i] = agg[n * 13 + i] * inv; xv[i] = x[n * 13 + i]; }
    float h[16];
#pragma unroll
    for (int o = 0; o < 16; o++) {
        float acc = sb[o];
#pragma unroll
        for (int i = 0; i < 13; i++) acc += a[i] * sWl[i * 16 + o] + xv[i] * sWr[i * 16 + o];
        h[o] = lrelu(acc);
    }
    float ya[8];
#pragma unroll
    for (int o2 = 0; o2 < 8; o2++) {
        float y = 0.0f, za = 0.0f;
#pragma unroll
        for (int o = 0; o < 16; o++) { y += h[o] * sA[o * 8 + o2]; za += h[o] * sB[o * 8 + o2]; }
        ya[o2] = y;
        z2[n * 8 + o2] = za;
    }
    uint4 out;
    out.x = pk(ya[0], ya[1]); out.y = pk(ya[2], ya[3]);
    out.z = pk(ya[4], ya[5]); out.w = pk(ya[6], ya[7]);
    *(uint4*)&y2b[(size_t)n * 4u] = out;
}

// ---- Layer-2 gather + fused epilogue: h2 (in z2), y3b ------------------
__global__ __launch_bounds__(256) void agg8f_k(const unsigned* __restrict__ y2b,
                                               const unsigned* __restrict__ binned,
                                               const int* __restrict__ offs,
                                               const float* __restrict__ cntf,
                                               const float* __restrict__ b2,
                                               const float* __restrict__ W3l,
                                               float* __restrict__ z2h2,
                                               unsigned* __restrict__ y3b,
                                               float* __restrict__ pool) {
    __shared__ float sb[8], sW3[32];
    if (blockIdx.x == 0) {
        for (int i = threadIdx.x; i < N_GRAPHS * 5; i += 256) pool[i] = 0.0f;
    }
    if (threadIdx.x < 8) sb[threadIdx.x] = b2[threadIdx.x];
    if (threadIdx.x < 32) sW3[threadIdx.x] = W3l[threadIdx.x];
    __syncthreads();
    int g = blockIdx.x * 256 + threadIdx.x;
    if (g >= N_NODES) return;
    int bin = g >> BINB, f = g & (WIN - 1);
    float a0 = 0, a1 = 0, a2 = 0, a3 = 0, a4 = 0, a5 = 0, a6 = 0, a7 = 0;
#pragma unroll
    for (int q = 0; q < 4; q++) {
        int sub = (bin << 2) | q;
        const int* o = offs + (size_t)sub * 513;
        int s = o[f], e = o[f + 1];
        const unsigned* bp = binned + (size_t)sub * CAPQ;
        int k = s;
        for (; k + 4 <= e; k += 4) {
            unsigned w0 = bp[k], w1 = bp[k + 1], w2 = bp[k + 2], w3 = bp[k + 3];
            uint4 v0 = *(const uint4*)&y2b[(size_t)(w0 & 0x3FFFFu) * 4u];
            uint4 v1 = *(const uint4*)&y2b[(size_t)(w1 & 0x3FFFFu) * 4u];
            uint4 v2 = *(const uint4*)&y2b[(size_t)(w2 & 0x3FFFFu) * 4u];
            uint4 v3 = *(const uint4*)&y2b[(size_t)(w3 & 0x3FFFFu) * 4u];
            a0 += blo(v0.x) + blo(v1.x) + blo(v2.x) + blo(v3.x);
            a1 += bhi(v0.x) + bhi(v1.x) + bhi(v2.x) + bhi(v3.x);
            a2 += blo(v0.y) + blo(v1.y) + blo(v2.y) + blo(v3.y);
            a3 += bhi(v0.y) + bhi(v1.y) + bhi(v2.y) + bhi(v3.y);
            a4 += blo(v0.z) + blo(v1.z) + blo(v2.z) + blo(v3.z);
            a5 += bhi(v0.z) + bhi(v1.z) + bhi(v2.z) + bhi(v3.z);
            a6 += blo(v0.w) + blo(v1.w) + blo(v2.w) + blo(v3.w);
            a7 += bhi(v0.w) + bhi(v1.w) + bhi(v2.w) + bhi(v3.w);
        }
        for (; k < e; k++) {
            uint4 v = *(const uint4*)&y2b[(size_t)(bp[k] & 0x3FFFFu) * 4u];
            a0 += blo(v.x); a1 += bhi(v.x); a2 += blo(v.y); a3 += bhi(v.y);
            a4 += blo(v.z); a5 += bhi(v.z); a6 += blo(v.w); a7 += bhi(v.w);
        }
    }
    float inv = 1.0f / fmaxf(cntf[g], 1.0f);
    float h2v[8];
    float s8[8] = {a0, a1, a2, a3, a4, a5, a6, a7};
#pragma unroll
    for (int j = 0; j < 8; j++) {
        float v = s8[j] * inv + sb[j] + z2h2[(size_t)g * 8 + j];
        h2v[j] = lrelu(v);
        z2h2[(size_t)g * 8 + j] = h2v[j];
    }
    float y[4];
#pragma unroll
    for (int k = 0; k < 4; k++) {
        float acc = 0.0f;
#pragma unroll
        for (int j = 0; j < 8; j++) acc += h2v[j] * sW3[j * 4 + k];
        y[k] = acc;
    }
    uint2 out;
    out.x = pk(y[0], y[1]); out.y = pk(y[2], y[3]);
    *(uint2*)&y3b[(size_t)g * 2u] = out;
}

// ---- Layer-3 gather + fused epilogue + pooling -------------------------
__global__ __launch_bounds__(256) void agg4pool_k(const unsigned* __restrict__ y3b,
                                                  const unsigned* __restrict__ binned,
                                                  const int* __restrict__ offs,
                                                  const float* __restrict__ cntf,
                                                  const float* __restrict__ h2,
                                                  const float* __restrict__ W3r,
                                                  const float* __restrict__ b3,
                                                  const int* __restrict__ batch,
                                                  float* __restrict__ pool,
                                                  float* __restrict__ gcnt) {
    __shared__ float sW[32], sb[4];
    __shared__ float lp[16][4];
    __shared__ float lc[16];
    __shared__ int sbase;
    if (threadIdx.x < 32) sW[threadIdx.x] = W3r[threadIdx.x];
    if (threadIdx.x < 4) sb[threadIdx.x] = b3[threadIdx.x];
    if (threadIdx.x < 16) {
        lc[threadIdx.x] = 0.0f;
        for (int k = 0; k < 4; k++) lp[threadIdx.x][k] = 0.0f;
    }
    int n0 = blockIdx.x * 256;
    if (threadIdx.x == 0) sbase = batch[n0 < N_NODES ? n0 : N_NODES - 1];
    __syncthreads();
    int g = n0 + threadIdx.x;
    if (g < N_NODES) {
        int bin = g >> BINB, f = g & (WIN - 1);
        float a0 = 0, a1 = 0, a2 = 0, a3 = 0;
#pragma unroll
        for (int q = 0; q < 4; q++) {
            int sub = (bin << 2) | q;
            const int* o = offs + (size_t)sub * 513;
            int s = o[f], e = o[f + 1];
            const unsigned* bp = binned + (size_t)sub * CAPQ;
            int k = s;
            for (; k + 4 <= e; k += 4) {
                unsigned w0 = bp[k], w1 = bp[k + 1], w2 = bp[k + 2], w3 = bp[k + 3];
                uint2 v0 = *(const uint2*)&y3b[(size_t)(w0 & 0x3FFFFu) * 2u];
                uint2 v1 = *(const uint2*)&y3b[(size_t)(w1 & 0x3FFFFu) * 2u];
                uint2 v2 = *(const uint2*)&y3b[(size_t)(w2 & 0x3FFFFu) * 2u];
                uint2 v3 = *(const uint2*)&y3b[(size_t)(w3 & 0x3FFFFu) * 2u];
                a0 += blo(v0.x) + blo(v1.x) + blo(v2.x) + blo(v3.x);
                a1 += bhi(v0.x) + bhi(v1.x) + bhi(v2.x) + bhi(v3.x);
                a2 += blo(v0.y) + blo(v1.y) + blo(v2.y) + blo(v3.y);
                a3 += bhi(v0.y) + bhi(v1.y) + bhi(v2.y) + bhi(v3.y);
            }
            for (; k < e; k++) {
                uint2 v = *(const uint2*)&y3b[(size_t)(bp[k] & 0x3FFFFu) * 2u];
                a0 += blo(v.x); a1 += bhi(v.x); a2 += blo(v.y); a3 += bhi(v.y);
            }
        }
        float inv = 1.0f / fmaxf(cntf[g], 1.0f);
        float s4[4] = {a0, a1, a2, a3};
        float h2v[8];
#pragma unroll
        for (int j = 0; j < 8; j++) h2v[j] = h2[(size_t)g * 8 + j];
        int b = batch[g];
        int off = b - sbase;
        bool local = (off >= 0 && off < 16);
#pragma unroll
        for (int k = 0; k < 4; k++) {
            float z = 0.0f;
#pragma unroll
            for (int j = 0; j < 8; j++) z += h2v[j] * sW[j * 4 + k];
            float v = s4[k] * inv + sb[k] + z;
            if (local) atomicAdd(&lp[off][k], v);
            else atomicAdd(&pool[b * 4 + k], v);
        }
        if (local) atomicAdd(&lc[off], 1.0f);
        else atomicAdd(&gcnt[b], 1.0f);
    }
    __syncthreads();
    if (threadIdx.x < 16) {
        int b = sbase + threadIdx.x;
        float c = lc[threadIdx.x];
        if (c > 0.0f && b < N_GRAPHS) {
            atomicAdd(&gcnt[b], c);
            for (int k = 0; k < 4; k++) atomicAdd(&pool[b * 4 + k], lp[threadIdx.x][k]);
        }
    }
}

__global__ __launch_bounds__(256) void final_k(const float* __restrict__ pool,
                                               const float* __restrict__ gcnt,
                                               const float* __restrict__ Wc,
                                               const float* __restrict__ bc,
                                               float* __restrict__ out) {
    int g = blockIdx.x * blockDim.x + threadIdx.x;
    if (g >= N_GRAPHS) return;
    float inv = 1.0f / fmaxf(gcnt[g], 1.0f);
    float acc = bc[0];
#pragma unroll
    for (int k = 0; k < 4; k++) {
        float ap = pool[g * 4 + k];
        acc += ap * inv * Wc[k] + ap * Wc[4 + k];
    }
    out[g] = acc;
}

extern "C" void kernel_launch(void* const* d_in, const int* in_sizes, int n_in,
                              void* d_out, int out_size, void* d_ws, size_t ws_size,
                              hipStream_t stream) {
    const float* x = (const float*)d_in[0];
    const int* ei = (const int*)d_in[1];
    const int* src = ei;
    const int* dst = ei + N_EDGES;
    const int* batch = (const int*)d_in[2];
    const float* W1l = (const float*)d_in[3];
    const float* b1 = (const float*)d_in[4];
    const float* W1r = (const float*)d_in[5];
    const float* W2l = (const float*)d_in[6];
    const float* b2 = (const float*)d_in[7];
    const float* W2r = (const float*)d_in[8];
    const float* W3l = (const float*)d_in[9];
    const float* b3 = (const float*)d_in[10];
    const float* W3r = (const float*)d_in[11];
    const float* Wc = (const float*)d_in[12];
    const float* bc = (const float*)d_in[13];
    float* out = (float*)d_out;

    const size_t N = N_NODES;
    unsigned* binned = (unsigned*)d_ws;                 // NSUB*CAPQ u32 ~= 20 MB
    int* qcnt = (int*)(binned + (size_t)NSUB * CAPQ);   // 2048 ints
    int* offs = qcnt + 2048;                            // NSUB*513 ints ~= 4 MB
    float* fbase = (float*)(offs + (size_t)NSUB * 513);
    float* agg = fbase;                         // 13N floats
    float* cntf = fbase + 13 * N;               // N
    float* z2 = cntf + N;                       // 8N (becomes h2 in place)
    unsigned* x16b = (unsigned*)(z2 + 8 * N);   // 8N u32
    unsigned* y2b = x16b + 8 * N;               // 4N u32
    unsigned* y3b = y2b + 4 * N;                // 2N u32
    float* pool = (float*)(y3b + 2 * N);        // 2048 (gcnt follows)
    float* gcnt = pool + N_GRAPHS * 4;          // 512

    const int TPB = 256;
    const int NB = (N_NODES + TPB - 1) / TPB;

    // 7 dispatches; zeroing folded into producers.
    pack_x<<<(N_NODES * 8 + TPB - 1) / TPB, TPB, 0, stream>>>(x, x16b, qcnt);
    partition_k<<<PART_BLOCKS, 1024, 0, stream>>>(src, dst, qcnt, binned);
    sortagg_k<<<NBINS, 1024, 0, stream>>>(x16b, binned, qcnt, offs, cntf, agg);
    fused1<<<NB, TPB, 0, stream>>>(agg, x, cntf, W1l, b1, W1r, W2l, W2r, y2b, z2);
    agg8f_k<<<NB, TPB, 0, stream>>>(y2b, binned, offs, cntf, b2, W3l, z2, y3b, pool);
    agg4pool_k<<<NB, TPB, 0, stream>>>(y3b, binned, offs, cntf, z2, W3r, b3, batch, pool, gcnt);
    final_k<<<2, TPB, 0, stream>>>(pool, gcnt, Wc, bc, out);
}